// Round 6
// baseline (2231.591 us; speedup 1.0000x reference)
//
#include <hip/hip_runtime.h>
#include <stdint.h>

#define DI __device__ __forceinline__

typedef short s16x8 __attribute__((ext_vector_type(8)));
typedef float f32x4 __attribute__((ext_vector_type(4)));

// ---- constants ----
#define NG   2048
#define NP   512
#define TT   100
#define BB   256
#define N4   8192   // 4*NG
#define MR   25600  // B*T
#define NBLK 256    // persistent grid size

DI unsigned short f32_to_bf16(float f) {
  union { float f; uint32_t u; } x; x.f = f;
  uint32_t r = x.u + 0x7fffu + ((x.u >> 16) & 1u);
  return (unsigned short)(r >> 16);
}

DI void async16(const void* g, void* l) {
  __builtin_amdgcn_global_load_lds((const __attribute__((address_space(1))) void*)g,
                                   (__attribute__((address_space(3))) void*)l,
                                   16, 0, 0);
}
DI void async4(const void* g, void* l) {
  __builtin_amdgcn_global_load_lds((const __attribute__((address_space(1))) void*)g,
                                   (__attribute__((address_space(3))) void*)l,
                                   4, 0, 0);
}

DI f32x4 mfma16(s16x8 a, s16x8 b, f32x4 c) {
  return __builtin_amdgcn_mfma_f32_16x16x32_bf16(a, b, c, 0, 0, 0);
}

// zero the producer-flag array (100 t x 4 mt, one 64B line each)
__global__ __launch_bounds__(256) void k_zero_flags(unsigned* p) {
  int i = blockIdx.x * 256 + threadIdx.x;
  if (i < TT * 4 * 16) p[i] = 0u;
}

// =====================================================================
// Pipelined bf16 MFMA core (non-persistent kernels) — unchanged.
// =====================================================================
template <int BM>
DI void gemm_core_p(const unsigned short* __restrict__ A, int lda, int m0,
                    const unsigned short* __restrict__ Bt, int ldb, int n0, int K,
                    unsigned short* sA, unsigned short* sB, f32x4* acc) {
  constexpr int FM = BM / 32;
  const int tid  = threadIdx.x;
  const int wave = tid >> 6;
  const int lane = tid & 63;
  const int quad = lane >> 4;
  const int lr   = lane & 15;
  const int wm   = wave >> 2;
  const int wn   = wave & 3;
  const int lr8  = lane >> 3;
  const int lc8  = lane & 7;
  const int scol = (lc8 ^ lr8) << 3;

  const int nkt = K >> 6;
  int buf = 0;

  auto stage = [&](int bsel, int k0) {
    unsigned short* dA = sA + bsel * (BM * 64);
    unsigned short* dB = sB + bsel * (128 * 64);
#pragma unroll
    for (int c = 0; c < BM / 64; ++c) {
      int rbase = wave * (BM / 8) + c * 8;
      const unsigned short* g = A + (size_t)(m0 + rbase + lr8) * lda + (k0 + scol);
      async16(g, dA + rbase * 64);
    }
#pragma unroll
    for (int c = 0; c < 2; ++c) {
      int rbase = wave * 16 + c * 8;
      const unsigned short* g = Bt + (size_t)(n0 + rbase + lr8) * ldb + (k0 + scol);
      async16(g, dB + rbase * 64);
    }
  };

  stage(0, 0);
  __syncthreads();
  for (int kt = 0; kt < nkt; ++kt) {
    if (kt + 1 < nkt) stage(buf ^ 1, (kt + 1) << 6);
    const char* cA = (const char*)(sA + buf * (BM * 64));
    const char* cB = (const char*)(sB + buf * (128 * 64));
#pragma unroll
    for (int ks = 0; ks < 2; ++ks) {
      s16x8 af[FM], bfr[2];
#pragma unroll
      for (int fm = 0; fm < FM; ++fm) {
        int row = wm * (BM / 2) + fm * 16 + lr;
        int off = row * 128 + ((ks * 64 + quad * 16) ^ ((row & 7) << 4));
        af[fm] = *(const s16x8*)(cA + off);
      }
#pragma unroll
      for (int fn = 0; fn < 2; ++fn) {
        int col = wn * 32 + fn * 16 + lr;
        int off = col * 128 + ((ks * 64 + quad * 16) ^ ((col & 7) << 4));
        bfr[fn] = *(const s16x8*)(cB + off);
      }
#pragma unroll
      for (int fm = 0; fm < FM; ++fm)
#pragma unroll
        for (int fn = 0; fn < 2; ++fn)
          acc[fm * 2 + fn] = mfma16(af[fm], bfr[fn], acc[fm * 2 + fn]);
    }
    __syncthreads();
    buf ^= 1;
  }
}

// =====================================================================
// Transpose + fp32->bf16. MODE 0: n = c + noff. MODE 1 (lstm_U gate/cell
// permutation): n = ((c&2047)>>4)*64 + ((c>>11)<<4) + (c&15)  — each
// 64-col group = 16 cells x 4 gates, so one lane's acc holds all 4 gates.
// =====================================================================
template <int MODE>
__global__ __launch_bounds__(256) void k_transpose_bf16(
    const float* __restrict__ src, unsigned short* __restrict__ dst,
    int R, int C, int noff) {
  __shared__ unsigned short tile[64][65];
  int tr0 = blockIdx.x * 64;
  int tc0 = blockIdx.y * 64;
  int tid = threadIdx.x;
#pragma unroll
  for (int i = 0; i < 16; ++i) {
    int idx = tid + i * 256;
    int r = idx >> 6, c = idx & 63;
    tile[r][c] = f32_to_bf16(src[(size_t)(tr0 + r) * C + (tc0 + c)]);
  }
  __syncthreads();
#pragma unroll
  for (int i = 0; i < 16; ++i) {
    int idx = tid + i * 256;
    int cc = idx >> 6, r = idx & 63;
    int c = tc0 + cc;
    int n = (MODE == 0) ? (c + noff)
                        : ((((c & 2047) >> 4) << 6) | (((c >> 11) & 3) << 4) | (c & 15));
    dst[(size_t)n * R + (tr0 + r)] = tile[r][cc];
  }
}

__global__ __launch_bounds__(256) void k_cvt(const float* __restrict__ src,
                                             unsigned short* __restrict__ dst, int n) {
  int i = blockIdx.x * 256 + threadIdx.x;
  if (i < n) dst[i] = f32_to_bf16(src[i]);
}

// ---- W2 = M_W @ lstm_W, bias2 = M_b @ lstm_W + lstm_b (gate-permuted) ----
__global__ __launch_bounds__(256) void k_prep_xw_part(
    const float* __restrict__ lstm_W, const float* __restrict__ M_W,
    const float* __restrict__ M_b, float* __restrict__ part) {
  int c = blockIdx.x * 256 + threadIdx.x;
  int kc = blockIdx.y;
  int k0 = kc * 128;
  float a0 = 0.f, a1 = 0.f, ab = 0.f;
  for (int k = k0; k < k0 + 128; ++k) {
    float w = lstm_W[(size_t)k * N4 + c];
    a0 += M_W[k] * w;
    a1 += M_W[NG + k] * w;
    ab += M_b[k] * w;
  }
  float* p = part + (size_t)kc * 3 * N4;
  p[c] = a0; p[N4 + c] = a1; p[2 * N4 + c] = ab;
}

__global__ __launch_bounds__(256) void k_prep_xw_reduce(
    const float* __restrict__ part, const float* __restrict__ lstm_b,
    float* __restrict__ W2r, float* __restrict__ b2r) {
  int c = blockIdx.x * 256 + threadIdx.x;
  float a0 = 0.f, a1 = 0.f, ab = 0.f;
  for (int kc = 0; kc < 16; ++kc) {
    const float* p = part + (size_t)kc * 3 * N4;
    a0 += p[c]; a1 += p[N4 + c]; ab += p[2 * N4 + c];
  }
  int n = (((c & 2047) >> 4) << 6) | (((c >> 11) & 3) << 4) | (c & 15);
  W2r[n] = a0; W2r[N4 + n] = a1; b2r[n] = ab + lstm_b[c];
}

// ---- encoders: [h0 | c0] = p0 @ [enc1_W ; enc2_W] packed as N=4096 ----
__global__ __launch_bounds__(512) void k_enc(
    const unsigned short* __restrict__ p0b, const unsigned short* __restrict__ encWt,
    const float* __restrict__ enc1_b, const float* __restrict__ enc2_b,
    unsigned short* __restrict__ hbf, float* __restrict__ cfp) {
  __shared__ __align__(16) unsigned short sA[2 * 64 * 64];
  __shared__ __align__(16) unsigned short sB[2 * 128 * 64];
  int m0 = blockIdx.x * 64, n0 = blockIdx.y * 128;
  const f32x4 vzero = {0.f, 0.f, 0.f, 0.f};
  f32x4 acc[4];
#pragma unroll
  for (int i = 0; i < 4; ++i) acc[i] = vzero;
  gemm_core_p<64>(p0b, NP, m0, encWt, NP, n0, NP, sA, sB, acc);

  const int tid = threadIdx.x, wave = tid >> 6, lane = tid & 63;
  const int quad = lane >> 4, lr = lane & 15, wm = wave >> 2, wn = wave & 3;
#pragma unroll
  for (int fm = 0; fm < 2; ++fm)
#pragma unroll
    for (int fn = 0; fn < 2; ++fn)
#pragma unroll
      for (int reg = 0; reg < 4; ++reg) {
        int grow = m0 + wm * 32 + fm * 16 + quad * 4 + reg;
        int gcol = n0 + wn * 32 + fn * 16 + lr;
        float val = acc[fm * 2 + fn][reg];
        if (gcol < NG)
          hbf[(size_t)grow * NG + gcol] = f32_to_bf16(val + enc1_b[gcol]);
        else
          cfp[(size_t)grow * NG + (gcol - NG)] = val + enc2_b[gcol - NG];
      }
}

// ---- persistent recurrence: all 100 LSTM steps ----
// 256 blocks (4 mt x 64 nt, XCD swizzle), 256 threads (4 waves, 2x2 of
// 32x64 wave tiles). Ring-5 LDS, counted vmcnt, register gate epilogue.
// Sync: per-(t,mt) producer counters (the 4 mt row-groups are INDEPENDENT
// recurrence chains — block (mt,nt) at t+1 reads h rows [mt*64,+64) which
// only blocks (mt,*) produce). No grid-wide barrier, no fences: h moves
// via agent-scope write-through stores + first-touch cached reads.
__global__ __launch_bounds__(256) void k_steps(
    const unsigned short* __restrict__ Ut,
    const float* __restrict__ vv, const float* __restrict__ W2r,
    const float* __restrict__ b2r, const float* __restrict__ cfp,
    const unsigned short* __restrict__ hb0,
    unsigned short* __restrict__ hs, unsigned* __restrict__ flags) {
  // A ring5 @0 (5x8KB), B ring5 @40960 (5x16KB), vvx @122880, vvy @123136,
  // htmp @123392 (4KB) -> 127488 B
  __shared__ __align__(16) char smem[127488];

  const int bid = blockIdx.x;
  const int xcd = bid & 7, sb = bid >> 3;
  const int mt = sb >> 3, nsub = sb & 7;
  const int nt = xcd * 8 + nsub;
  const int m0 = mt * 64, n0 = nt * 128;
  const int tid = threadIdx.x;
  const int wave = tid >> 6, lane = tid & 63;
  const int quad = lane >> 4, lr = lane & 15;
  const int wm = wave >> 1, wn = wave & 1;
  const int lr8 = lane >> 3, lc8 = lane & 7;
  const int scol = (lc8 ^ lr8) << 3;

  // ---- t-invariant state in registers ----
  float w2x[4], w2y[4], bz[4];
#pragma unroll
  for (int g = 0; g < 4; ++g) {
    const int idx = n0 + wn * 64 + g * 16 + lr;
    w2x[g] = W2r[idx]; w2y[g] = W2r[N4 + idx]; bz[g] = b2r[idx];
    asm volatile("" : "+v"(w2x[g])); asm volatile("" : "+v"(w2y[g]));
    asm volatile("" : "+v"(bz[g]));
  }
  const int cellg = nt * 32 + wn * 16 + lr;       // this thread's cell
  float cst[2][4];
#pragma unroll
  for (int fm = 0; fm < 2; ++fm)
#pragma unroll
    for (int reg = 0; reg < 4; ++reg) {
      const int r = wm * 32 + fm * 16 + quad * 4 + reg;
      cst[fm][reg] = cfp[(size_t)(m0 + r) * NG + cellg];
      asm volatile("" : "+v"(cst[fm][reg]));
    }

  // hoisted global base pointers (per-wave, loop-invariant)
  const unsigned short* bw = Ut + (size_t)(n0 + wave * 32 + lr8) * NG + scol;
  unsigned* const flagp = flags + (TT * 0 + 0) * 0 + 0;  // (kept simple below)

  auto stageB = [&](int slot, int k) {            // 4 ops per wave
    char* dB = smem + 40960 + slot * 16384 + (wave * 32) * 128;
#pragma unroll
    for (int c = 0; c < 4; ++c)
      async16(bw + (size_t)(c * 8) * NG + k, dB + c * 1024);
  };
  auto stageV = [&](int t) {                      // 2 ops per wave
    const float* gx = vv + ((size_t)(m0 + lane) * TT + t) * 2;
    async4(gx, smem + 122880);
    async4(gx + 1, smem + 123136);
  };

  f32x4 acc[8];
  auto computeS = [&](int slot) {
    const char* cA = smem + slot * 8192;
    const char* cB = smem + 40960 + slot * 16384;
#pragma unroll
    for (int ks = 0; ks < 2; ++ks) {
      s16x8 af[2], bfr[4];
#pragma unroll
      for (int fm = 0; fm < 2; ++fm) {
        const int row = wm * 32 + fm * 16 + lr;
        af[fm] = *(const s16x8*)(cA + row * 128 + ((ks * 64 + quad * 16) ^ ((row & 7) << 4)));
      }
#pragma unroll
      for (int fn = 0; fn < 4; ++fn) {
        const int col = wn * 64 + fn * 16 + lr;
        bfr[fn] = *(const s16x8*)(cB + col * 128 + ((ks * 64 + quad * 16) ^ ((col & 7) << 4)));
      }
#pragma unroll
      for (int fm = 0; fm < 2; ++fm)
#pragma unroll
        for (int fn = 0; fn < 4; ++fn)
          acc[fm * 4 + fn] = mfma16(af[fm], bfr[fn], acc[fm * 4 + fn]);
    }
  };

#define INC5(x) x = ((x) == 4) ? 0 : ((x) + 1)
#define PHASE(W)  asm volatile("s_waitcnt vmcnt(" #W ")\n\ts_barrier" ::: "memory"); \
                  computeS(cs); INC5(cs);

  asm volatile("s_waitcnt vmcnt(0)" ::: "memory");  // exact counting baseline
  int cs = 0;
  stageB(0, 0); stageB(1, 64); stageB(2, 128);      // t=0 B prefetch (12 ops)

  for (int t = 0; t < TT; ++t) {
    const unsigned short* hin = t ? hs + (size_t)(t - 1) * BB * NG : hb0;
    const unsigned short* aw = hin + (size_t)(m0 + wave * 16 + lr8) * NG + scol;
    auto stageA = [&](int slot, int kt) {         // 2 ops per wave
      char* dA = smem + slot * 8192 + (wave * 16) * 128;
      async16(aw + kt * 64, dA);
      async16(aw + (size_t)8 * NG + kt * 64, dA + 1024);
    };

    // entry: A into slots cs..cs+2 (B already prefetched there)
    { int s1 = cs; stageA(s1, 0); INC5(s1); stageA(s1, 1); INC5(s1); stageA(s1, 2); }
    stageV(t);
    const f32x4 vzero = {0.f, 0.f, 0.f, 0.f};
#pragma unroll
    for (int i = 0; i < 8; ++i) acc[i] = vzero;

    int ss = cs; INC5(ss); INC5(ss); INC5(ss);    // stage slot = cs+3
    stageB(ss, 3 << 6); stageA(ss, 3); INC5(ss);
    PHASE(12)
    stageB(ss, 4 << 6); stageA(ss, 4); INC5(ss);
    PHASE(16)
    stageB(ss, 5 << 6); stageA(ss, 5); INC5(ss);
    PHASE(20)
#pragma unroll
    for (int p = 3; p <= 28; ++p) {
      stageB(ss, (p + 3) << 6); stageA(ss, p + 3); INC5(ss);
      PHASE(18)
    }
    // phases 29..31: no staging (next-step B staged after h-stores)
    PHASE(12)
    PHASE(6)
    PHASE(0)
    __syncthreads();                 // all waves done with LDS before htmp use

    // ---- register gate epilogue ----
    const float* vx = (const float*)(smem + 122880);
    const float* vy = (const float*)(smem + 123136);
    unsigned short* htmp = (unsigned short*)(smem + 123392);
#pragma unroll
    for (int fm = 0; fm < 2; ++fm)
#pragma unroll
      for (int reg = 0; reg < 4; ++reg) {
        const int r = wm * 32 + fm * 16 + quad * 4 + reg;
        const float ax = vx[r], ay = vy[r];
        float zi = acc[fm * 4 + 0][reg] + ax * w2x[0] + ay * w2y[0] + bz[0];
        float zf = acc[fm * 4 + 1][reg] + ax * w2x[1] + ay * w2y[1] + bz[1];
        float zg = acc[fm * 4 + 2][reg] + ax * w2x[2] + ay * w2y[2] + bz[2];
        float zo = acc[fm * 4 + 3][reg] + ax * w2x[3] + ay * w2y[3] + bz[3];
        float i_ = 1.f / (1.f + __expf(-zi));
        float f_ = 1.f / (1.f + __expf(-zf));
        float g_ = fmaxf(zg, 0.f);
        float o_ = 1.f / (1.f + __expf(-zo));
        float cn = f_ * cst[fm][reg] + i_ * g_;
        cst[fm][reg] = cn;
        htmp[r * 32 + wn * 16 + lr] = f32_to_bf16(o_ * fmaxf(cn, 0.f));
      }
    __syncthreads();
    // coalesced 4B write-through h stores into hs[t]
    const unsigned* hw = (const unsigned*)htmp;
#pragma unroll
    for (int p = 0; p < 4; ++p) {
      const int q = tid + p * 256;       // 0..1023 uints (64 rows x 16)
      const int r = q >> 4, cq = q & 15;
      unsigned* hp = (unsigned*)(hs + ((size_t)t * BB + m0 + r) * NG) + (nt * 16 + cq);
      __hip_atomic_store(hp, hw[q], __ATOMIC_RELAXED, __HIP_MEMORY_SCOPE_AGENT);
    }

    if (t + 1 < TT) {
      // next-step B prefetch AFTER h-stores: vmcnt(12) retires the 4 stores
      // (older) while keeping the 12 B loads in flight across the boundary.
      stageB(ss, 0); INC5(ss);
      stageB(ss, 64); INC5(ss);
      stageB(ss, 128); INC5(ss);
      asm volatile("s_waitcnt vmcnt(12)" ::: "memory");
      asm volatile("s_barrier" ::: "memory");      // all waves' stores retired
      if (tid == 0) {
        unsigned* fp = flags + (t * 4 + mt) * 16;
        __hip_atomic_fetch_add(fp, 1u, __ATOMIC_RELAXED, __HIP_MEMORY_SCOPE_AGENT);
        while (__hip_atomic_load(fp, __ATOMIC_RELAXED, __HIP_MEMORY_SCOPE_AGENT) < 64u)
          __builtin_amdgcn_s_sleep(2);
      }
      asm volatile("s_barrier" ::: "memory");      // release: hs[t] row-group ready
    }
  }
#undef PHASE
#undef INC5
  (void)flagp;
}

// ---- g_cells = relu(hs @ dense_W + dense_b) -> bf16 ----
__global__ __launch_bounds__(512) void k_dense(
    const unsigned short* __restrict__ hs, const unsigned short* __restrict__ dWt,
    const float* __restrict__ dense_b, unsigned short* __restrict__ gc) {
  __shared__ __align__(16) unsigned short sA[2 * 128 * 64];
  __shared__ __align__(16) unsigned short sB[2 * 128 * 64];
  int bid = blockIdx.x;
  int mt = bid >> 4;
  int r4 = bid & 15;
  int nt = ((r4 & 7) << 1) | (r4 >> 3);   // fixed nt pair per XCD
  int m0 = mt * 128, n0 = nt * 128;
  const f32x4 vzero = {0.f, 0.f, 0.f, 0.f};
  f32x4 acc[8];
#pragma unroll
  for (int i = 0; i < 8; ++i) acc[i] = vzero;
  gemm_core_p<128>(hs, NG, m0, dWt, NG, n0, NG, sA, sB, acc);

  const int tid = threadIdx.x, wave = tid >> 6, lane = tid & 63;
  const int quad = lane >> 4, lr = lane & 15, wm = wave >> 2, wn = wave & 3;
#pragma unroll
  for (int fm = 0; fm < 4; ++fm)
#pragma unroll
    for (int fn = 0; fn < 2; ++fn)
#pragma unroll
      for (int reg = 0; reg < 4; ++reg) {
        int grow = m0 + wm * 64 + fm * 16 + quad * 4 + reg;
        int gcol = n0 + wn * 32 + fn * 16 + lr;
        float val = fmaxf(acc[fm * 2 + fn][reg] + dense_b[gcol], 0.f);
        gc[(size_t)grow * NG + gcol] = f32_to_bf16(val);
      }
}

// ---- place_preds = g_cells @ dec_W + dec_b (fp32 out, [B][T][Np]) ----
__global__ __launch_bounds__(512) void k_dec(
    const unsigned short* __restrict__ gc, const unsigned short* __restrict__ decWt,
    const float* __restrict__ dec_b, float* __restrict__ out) {
  __shared__ __align__(16) unsigned short sA[2 * 128 * 64];
  __shared__ __align__(16) unsigned short sB[2 * 128 * 64];
  int m0 = blockIdx.x * 128, n0 = blockIdx.y * 128;
  const f32x4 vzero = {0.f, 0.f, 0.f, 0.f};
  f32x4 acc[8];
#pragma unroll
  for (int i = 0; i < 8; ++i) acc[i] = vzero;
  gemm_core_p<128>(gc, NG, m0, decWt, NG, n0, NG, sA, sB, acc);

  const int tid = threadIdx.x, wave = tid >> 6, lane = tid & 63;
  const int quad = lane >> 4, lr = lane & 15, wm = wave >> 2, wn = wave & 3;
#pragma unroll
  for (int fm = 0; fm < 4; ++fm)
#pragma unroll
    for (int fn = 0; fn < 2; ++fn)
#pragma unroll
      for (int reg = 0; reg < 4; ++reg) {
        int grow = m0 + wm * 64 + fm * 16 + quad * 4 + reg;   // t*256+b
        int gcol = n0 + wn * 32 + fn * 16 + lr;               // 0..511
        int tt = grow >> 8, b = grow & 255;
        out[((size_t)b * TT + tt) * NP + gcol] = acc[fm * 2 + fn][reg] + dec_b[gcol];
      }
}

// =====================================================================
extern "C" void kernel_launch(void* const* d_in, const int* in_sizes, int n_in,
                              void* d_out, int out_size, void* d_ws, size_t ws_size,
                              hipStream_t stream) {
  (void)in_sizes; (void)n_in; (void)out_size; (void)ws_size;
  const float* v       = (const float*)d_in[0];
  const float* p0      = (const float*)d_in[1];
  const float* enc1_W  = (const float*)d_in[2];
  const float* enc1_b  = (const float*)d_in[3];
  const float* enc2_W  = (const float*)d_in[4];
  const float* enc2_b  = (const float*)d_in[5];
  const float* M_W     = (const float*)d_in[6];
  const float* M_b     = (const float*)d_in[7];
  const float* lstm_W  = (const float*)d_in[8];
  const float* lstm_U  = (const float*)d_in[9];
  const float* lstm_b  = (const float*)d_in[10];
  const float* dense_W = (const float*)d_in[11];
  const float* dense_b = (const float*)d_in[12];
  const float* dec_W   = (const float*)d_in[13];
  const float* dec_b   = (const float*)d_in[14];
  float* out = (float*)d_out;

  char* ws = (char*)d_ws;
  size_t off = 0;
  auto alloc = [&](size_t bytes) {
    char* p = ws + off;
    off += (bytes + 255) & ~(size_t)255;
    return p;
  };
  unsigned short* Ut    = (unsigned short*)alloc((size_t)N4 * NG * 2);   // 32 MB
  unsigned short* dWt   = (unsigned short*)alloc((size_t)NG * NG * 2);   // 8 MB
  unsigned short* decWt = (unsigned short*)alloc((size_t)NP * NG * 2);   // 2 MB
  unsigned short* encWt = (unsigned short*)alloc((size_t)2 * NG * NP * 2);
  unsigned short* p0b   = (unsigned short*)alloc((size_t)BB * NP * 2);
  float* W2r  = (float*)alloc((size_t)2 * N4 * 4);
  float* b2r  = (float*)alloc((size_t)N4 * 4);
  float* part = (float*)alloc((size_t)16 * 3 * N4 * 4);
  float* cfp  = (float*)alloc((size_t)BB * NG * 4);
  unsigned short* hb0 = (unsigned short*)alloc((size_t)BB * NG * 2);
  unsigned short* hs  = (unsigned short*)alloc((size_t)MR * NG * 2);     // 100 MB
  unsigned short* gc  = (unsigned short*)alloc((size_t)MR * NG * 2);     // 100 MB
  unsigned* flags = (unsigned*)alloc((size_t)TT * 4 * 16 * 4);           // producer counters

  dim3 blk(256), blk5(512);
  // flag init (fresh every launch/replay)
  k_zero_flags<<<dim3(25), blk, 0, stream>>>(flags);
  // weight conversion / transposes
  k_transpose_bf16<1><<<dim3(32, 128), blk, 0, stream>>>(lstm_U, Ut, NG, N4, 0);
  k_transpose_bf16<0><<<dim3(32, 32), blk, 0, stream>>>(dense_W, dWt, NG, NG, 0);
  k_transpose_bf16<0><<<dim3(32, 8), blk, 0, stream>>>(dec_W, decWt, NG, NP, 0);
  k_transpose_bf16<0><<<dim3(8, 32), blk, 0, stream>>>(enc1_W, encWt, NP, NG, 0);
  k_transpose_bf16<0><<<dim3(8, 32), blk, 0, stream>>>(enc2_W, encWt, NP, NG, NG);
  k_cvt<<<dim3(512), blk, 0, stream>>>(p0, p0b, BB * NP);
  // rank-2 collapse of input path
  k_prep_xw_part<<<dim3(32, 16), blk, 0, stream>>>(lstm_W, M_W, M_b, part);
  k_prep_xw_reduce<<<dim3(32), blk, 0, stream>>>(part, lstm_b, W2r, b2r);
  // initial state
  k_enc<<<dim3(4, 32), blk5, 0, stream>>>(p0b, encWt, enc1_b, enc2_b, hb0, cfp);
  // recurrence: one persistent kernel, 100 steps, producer-flag sync
  k_steps<<<dim3(NBLK), blk, 0, stream>>>(Ut, v, W2r, b2r, cfp, hb0, hs, flags);
  // readout
  k_dense<<<dim3(3200), blk5, 0, stream>>>(hs, dWt, dense_b, gc);
  k_dec<<<dim3(200, 4), blk5, 0, stream>>>(gc, decWt, dec_b, out);
}